// Round 1
// baseline (7490.496 us; speedup 1.0000x reference)
//
#include <hip/hip_runtime.h>
#include <math.h>

#define E_NUM 320000
#define N_NUM 10000
#define NBLK  ((N_NUM + 63) / 64)   // 157

__device__ __forceinline__ float ssp_f(float x) {
    // softplus(x) - log(2), stable: max(x,0) + log(1+exp(-|x|)) - log2
    return fmaxf(x, 0.f) + __logf(1.f + __expf(-fabsf(x))) - 0.69314718056f;
}

// ---------------------------------------------------------------------------
// h[n][c] = emb[x[n]][c]
__global__ __launch_bounds__(256) void embed_kernel(const int* __restrict__ x,
                                                    const float* __restrict__ emb,
                                                    float* __restrict__ h) {
    int idx = blockIdx.x * 256 + threadIdx.x;       // exact: N*128 = 5000*256
    int n = idx >> 7, c = idx & 127;
    h[idx] = emb[x[n] * 128 + c];
}

// ---------------------------------------------------------------------------
// out[M][128] = op(A[M][128]) @ B[128][128] (+bias[128]) (+res[M][128])
// op = ssp if SSPA. Tile: 64 rows/block, 256 threads, 4x8 register blocking.
template <bool SSPA, bool BIAS, bool RES>
__global__ __launch_bounds__(256) void gemm128(const float* __restrict__ A,
                                               const float* __restrict__ B,
                                               const float* __restrict__ bias,
                                               const float* __restrict__ res,
                                               float* __restrict__ out, int M) {
    __shared__ float AT[128][68];   // k-major A tile, padded stride (272B, 16B-aligned)
    const int tid = threadIdx.x;
    const int row0 = blockIdx.x * 64;

    for (int i = tid; i < 64 * 128; i += 256) {
        int r = i >> 7, c = i & 127;
        float v = (row0 + r < M) ? A[(row0 + r) * 128 + c] : 0.f;
        if (SSPA) v = ssp_f(v);
        AT[c][r] = v;
    }
    __syncthreads();

    const int eg = tid & 15;   // row group: rows eg*4 .. eg*4+3
    const int jg = tid >> 4;   // col group: cols jg*8 .. jg*8+7
    float acc[4][8];
    #pragma unroll
    for (int i = 0; i < 4; ++i)
        #pragma unroll
        for (int j = 0; j < 8; ++j) acc[i][j] = 0.f;

    const float* Bj = B + jg * 8;
    #pragma unroll 4
    for (int k = 0; k < 128; ++k) {
        float4 a = *(const float4*)&AT[k][eg * 4];
        float b[8];
        *(float4*)&b[0] = *(const float4*)(Bj + k * 128);
        *(float4*)&b[4] = *(const float4*)(Bj + k * 128 + 4);
        float av[4] = {a.x, a.y, a.z, a.w};
        #pragma unroll
        for (int i = 0; i < 4; ++i)
            #pragma unroll
            for (int j = 0; j < 8; ++j) acc[i][j] = fmaf(av[i], b[j], acc[i][j]);
    }

    float bv[8];
    if (BIAS) {
        *(float4*)&bv[0] = *(const float4*)(bias + jg * 8);
        *(float4*)&bv[4] = *(const float4*)(bias + jg * 8 + 4);
    }
    #pragma unroll
    for (int i = 0; i < 4; ++i) {
        int r = row0 + eg * 4 + i;
        if (r < M) {
            #pragma unroll
            for (int j = 0; j < 8; ++j) {
                float v = acc[i][j];
                if (BIAS) v += bv[j];
                int c = jg * 8 + j;
                if (RES) v += res[r * 128 + c];
                out[r * 128 + c] = v;
            }
        }
    }
}

// ---------------------------------------------------------------------------
// Fused per-edge: ea = exp(coeff*(d-off)^2)  [64 x 50]
//   hidden = ssp(ea @ w1 + b1)               [64 x 128]
//   W      = (hidden @ w2 + b2) * C(d)       [64 x 128]
//   atomicAdd(agg[dst], xf[src] * W)
__global__ __launch_bounds__(256) void edge_kernel(const int* __restrict__ ei,
                                                   const float* __restrict__ dist,
                                                   const float* __restrict__ w1,
                                                   const float* __restrict__ b1,
                                                   const float* __restrict__ w2,
                                                   const float* __restrict__ b2,
                                                   const float* __restrict__ xf,
                                                   float* __restrict__ agg) {
    __shared__ float eaT[50][68];    // gaussian-major
    __shared__ float hT[128][68];    // k-major hidden
    __shared__ int s_src[64], s_dst[64];
    __shared__ float s_C[64], s_d[64];

    const int tid = threadIdx.x;
    const int e0 = blockIdx.x * 64;

    if (tid < 64) {
        int e = e0 + tid;
        s_src[tid] = ei[e];
        s_dst[tid] = ei[E_NUM + e];
        float d = dist[e];
        s_d[tid] = d;
        s_C[tid] = 0.5f * (__cosf(d * 0.31415926535f) + 1.0f);   // pi/10
    }
    __syncthreads();

    const float STEP = 10.0f / 49.0f;
    const float COEFF = -0.5f / (STEP * STEP);
    for (int i = tid; i < 50 * 64; i += 256) {
        int k = i >> 6, e = i & 63;
        float t = s_d[e] - k * STEP;
        eaT[k][e] = __expf(COEFF * t * t);
    }
    __syncthreads();

    const int eg = tid & 15;   // edges eg*4 .. +3
    const int jg = tid >> 4;   // cols  jg*8 .. +7

    // GEMM1: hidden = eaT^T @ w1   (K = 50)
    float acc[4][8];
    #pragma unroll
    for (int i = 0; i < 4; ++i)
        #pragma unroll
        for (int j = 0; j < 8; ++j) acc[i][j] = 0.f;
    {
        const float* Bj = w1 + jg * 8;
        #pragma unroll 2
        for (int k = 0; k < 50; ++k) {
            float4 a = *(const float4*)&eaT[k][eg * 4];
            float b[8];
            *(float4*)&b[0] = *(const float4*)(Bj + k * 128);
            *(float4*)&b[4] = *(const float4*)(Bj + k * 128 + 4);
            float av[4] = {a.x, a.y, a.z, a.w};
            #pragma unroll
            for (int i = 0; i < 4; ++i)
                #pragma unroll
                for (int j = 0; j < 8; ++j) acc[i][j] = fmaf(av[i], b[j], acc[i][j]);
        }
    }
    // bias + ssp, store transposed for GEMM2
    {
        float b1v[8];
        *(float4*)&b1v[0] = *(const float4*)(b1 + jg * 8);
        *(float4*)&b1v[4] = *(const float4*)(b1 + jg * 8 + 4);
        #pragma unroll
        for (int j = 0; j < 8; ++j) {
            float4 v;
            v.x = ssp_f(acc[0][j] + b1v[j]);
            v.y = ssp_f(acc[1][j] + b1v[j]);
            v.z = ssp_f(acc[2][j] + b1v[j]);
            v.w = ssp_f(acc[3][j] + b1v[j]);
            *(float4*)&hT[jg * 8 + j][eg * 4] = v;
        }
    }
    __syncthreads();

    // GEMM2: W = hT^T @ w2   (K = 128)
    float acc2[4][8];
    #pragma unroll
    for (int i = 0; i < 4; ++i)
        #pragma unroll
        for (int j = 0; j < 8; ++j) acc2[i][j] = 0.f;
    {
        const float* Bj = w2 + jg * 8;
        #pragma unroll 4
        for (int k = 0; k < 128; ++k) {
            float4 a = *(const float4*)&hT[k][eg * 4];
            float b[8];
            *(float4*)&b[0] = *(const float4*)(Bj + k * 128);
            *(float4*)&b[4] = *(const float4*)(Bj + k * 128 + 4);
            float av[4] = {a.x, a.y, a.z, a.w};
            #pragma unroll
            for (int i = 0; i < 4; ++i)
                #pragma unroll
                for (int j = 0; j < 8; ++j) acc2[i][j] = fmaf(av[i], b[j], acc2[i][j]);
        }
    }

    // epilogue: bias, cutoff scale, gather xf[src], scatter-add into agg[dst]
    float bv[8];
    *(float4*)&bv[0] = *(const float4*)(b2 + jg * 8);
    *(float4*)&bv[4] = *(const float4*)(b2 + jg * 8 + 4);
    #pragma unroll
    for (int i = 0; i < 4; ++i) {
        int e = eg * 4 + i;
        int sn = s_src[e], dn = s_dst[e];
        float Cv = s_C[e];
        const float* xr = xf + sn * 128 + jg * 8;
        float xv[8];
        *(float4*)&xv[0] = *(const float4*)(xr);
        *(float4*)&xv[4] = *(const float4*)(xr + 4);
        float* ar = agg + dn * 128 + jg * 8;
        #pragma unroll
        for (int j = 0; j < 8; ++j) {
            float wv = (acc2[i][j] + bv[j]) * Cv;
            atomicAdd(ar + j, xv[j] * wv);
        }
    }
}

// ---------------------------------------------------------------------------
// head: t = ssp(h@w1+b1); t = t@w2+b2; gs += colsum(t)   (gs: [64])
__global__ __launch_bounds__(256) void head_kernel(const float* __restrict__ h,
                                                   const float* __restrict__ w1,
                                                   const float* __restrict__ b1,
                                                   const float* __restrict__ w2,
                                                   const float* __restrict__ b2,
                                                   float* __restrict__ gs, int M) {
    __shared__ float hT[128][68];
    __shared__ float t1T[64][68];
    __shared__ float red[16][64];
    const int tid = threadIdx.x;
    const int row0 = blockIdx.x * 64;

    for (int i = tid; i < 64 * 128; i += 256) {
        int r = i >> 7, c = i & 127;
        hT[c][r] = (row0 + r < M) ? h[(row0 + r) * 128 + c] : 0.f;
    }
    __syncthreads();

    const int rg = tid & 15;   // rows rg*4 .. +3
    const int cg = tid >> 4;   // cols cg*4 .. +3

    float acc[4][4];
    #pragma unroll
    for (int i = 0; i < 4; ++i)
        #pragma unroll
        for (int j = 0; j < 4; ++j) acc[i][j] = 0.f;
    #pragma unroll 4
    for (int k = 0; k < 128; ++k) {
        float4 a = *(const float4*)&hT[k][rg * 4];
        float4 b = *(const float4*)(w1 + k * 64 + cg * 4);
        float av[4] = {a.x, a.y, a.z, a.w};
        float bb[4] = {b.x, b.y, b.z, b.w};
        #pragma unroll
        for (int i = 0; i < 4; ++i)
            #pragma unroll
            for (int j = 0; j < 4; ++j) acc[i][j] = fmaf(av[i], bb[j], acc[i][j]);
    }
    {
        float4 b1v = *(const float4*)(b1 + cg * 4);
        float bb[4] = {b1v.x, b1v.y, b1v.z, b1v.w};
        #pragma unroll
        for (int j = 0; j < 4; ++j) {
            float4 v;
            v.x = ssp_f(acc[0][j] + bb[j]);
            v.y = ssp_f(acc[1][j] + bb[j]);
            v.z = ssp_f(acc[2][j] + bb[j]);
            v.w = ssp_f(acc[3][j] + bb[j]);
            *(float4*)&t1T[cg * 4 + j][rg * 4] = v;
        }
    }
    __syncthreads();

    float acc2[4][4];
    #pragma unroll
    for (int i = 0; i < 4; ++i)
        #pragma unroll
        for (int j = 0; j < 4; ++j) acc2[i][j] = 0.f;
    #pragma unroll 4
    for (int k = 0; k < 64; ++k) {
        float4 a = *(const float4*)&t1T[k][rg * 4];
        float4 b = *(const float4*)(w2 + k * 64 + cg * 4);
        float av[4] = {a.x, a.y, a.z, a.w};
        float bb[4] = {b.x, b.y, b.z, b.w};
        #pragma unroll
        for (int i = 0; i < 4; ++i)
            #pragma unroll
            for (int j = 0; j < 4; ++j) acc2[i][j] = fmaf(av[i], bb[j], acc2[i][j]);
    }
    {
        float4 b2v = *(const float4*)(b2 + cg * 4);
        float bb[4] = {b2v.x, b2v.y, b2v.z, b2v.w};
        float cs[4] = {0.f, 0.f, 0.f, 0.f};
        #pragma unroll
        for (int i = 0; i < 4; ++i) {
            if (row0 + rg * 4 + i < M) {
                #pragma unroll
                for (int j = 0; j < 4; ++j) cs[j] += acc2[i][j] + bb[j];
            }
        }
        #pragma unroll
        for (int j = 0; j < 4; ++j) red[rg][cg * 4 + j] = cs[j];
    }
    __syncthreads();
    if (tid < 64) {
        float s = 0.f;
        #pragma unroll
        for (int r = 0; r < 16; ++r) s += red[r][tid];
        atomicAdd(&gs[tid], s);
    }
}

// out[i] = ro_b[i] + sum_k gs[k] * ro_w[k][i]
__global__ void final_kernel(const float* __restrict__ gs,
                             const float* __restrict__ ro_w,
                             const float* __restrict__ ro_b,
                             float* __restrict__ out) {
    int i = threadIdx.x;
    if (i < 12) {
        float s = ro_b[i];
        for (int k = 0; k < 64; ++k) s = fmaf(gs[k], ro_w[k * 12 + i], s);
        out[i] = s;
    }
}

// ---------------------------------------------------------------------------
extern "C" void kernel_launch(void* const* d_in, const int* in_sizes, int n_in,
                              void* d_out, int out_size, void* d_ws, size_t ws_size,
                              hipStream_t stream) {
    const int*   x      = (const int*)d_in[0];
    const int*   ei     = (const int*)d_in[1];
    const float* dist   = (const float*)d_in[2];
    const float* emb    = (const float*)d_in[3];
    const float* mlp_w1 = (const float*)d_in[4];
    const float* mlp_b1 = (const float*)d_in[5];
    const float* mlp_w2 = (const float*)d_in[6];
    const float* mlp_b2 = (const float*)d_in[7];
    const float* lin1_w = (const float*)d_in[8];
    const float* lin2_w = (const float*)d_in[9];
    const float* lin2_b = (const float*)d_in[10];
    const float* lin_w  = (const float*)d_in[11];
    const float* lin_b  = (const float*)d_in[12];
    const float* out1_w = (const float*)d_in[13];
    const float* out1_b = (const float*)d_in[14];
    const float* out2_w = (const float*)d_in[15];
    const float* out2_b = (const float*)d_in[16];
    const float* ro_w   = (const float*)d_in[17];
    const float* ro_b   = (const float*)d_in[18];
    float* out = (float*)d_out;

    float* h   = (float*)d_ws;          // [N][128]
    float* xf  = h + N_NUM * 128;       // [N][128], doubles as conv buffer
    float* agg = xf + N_NUM * 128;      // [N][128]
    float* gs  = agg + N_NUM * 128;     // [64]

    embed_kernel<<<N_NUM * 128 / 256, 256, 0, stream>>>(x, emb, h);

    for (int l = 0; l < 6; ++l) {
        // xf = h @ lin1_w[l]
        gemm128<false, false, false><<<NBLK, 256, 0, stream>>>(
            h, lin1_w + l * 16384, nullptr, nullptr, xf, N_NUM);
        hipMemsetAsync(agg, 0, (size_t)N_NUM * 128 * sizeof(float), stream);
        edge_kernel<<<E_NUM / 64, 256, 0, stream>>>(
            ei, dist, mlp_w1 + l * 6400, mlp_b1 + l * 128,
            mlp_w2 + l * 16384, mlp_b2 + l * 128, xf, agg);
        // conv = agg @ lin2_w[l] + lin2_b[l]   (into xf, now free)
        gemm128<false, true, false><<<NBLK, 256, 0, stream>>>(
            agg, lin2_w + l * 16384, lin2_b + l * 128, nullptr, xf, N_NUM);
        // h = h + ssp(conv) @ lin_w[l] + lin_b[l]
        gemm128<true, true, true><<<NBLK, 256, 0, stream>>>(
            xf, lin_w + l * 16384, lin_b + l * 128, h, h, N_NUM);
    }

    hipMemsetAsync(gs, 0, 64 * sizeof(float), stream);
    head_kernel<<<NBLK, 256, 0, stream>>>(h, out1_w, out1_b, out2_w, out2_b, gs, N_NUM);
    final_kernel<<<1, 64, 0, stream>>>(gs, ro_w, ro_b, out);
}

// Round 2
// 922.358 us; speedup vs baseline: 8.1210x; 8.1210x over previous
//
#include <hip/hip_runtime.h>
#include <math.h>

#define E_NUM 320000
#define N_NUM 10000
#define NBLK  ((N_NUM + 63) / 64)   // 157
#define TAB   4096

__device__ __forceinline__ float ssp_f(float x) {
    // softplus(x) - log(2), stable: max(x,0) + log(1+exp(-|x|)) - log2
    return fmaxf(x, 0.f) + __logf(1.f + __expf(-fabsf(x))) - 0.69314718056f;
}

// ---------------------------------------------------------------------------
// h[n][c] = emb[x[n]][c]
__global__ __launch_bounds__(256) void embed_kernel(const int* __restrict__ x,
                                                    const float* __restrict__ emb,
                                                    float* __restrict__ h) {
    int idx = blockIdx.x * 256 + threadIdx.x;       // exact: N*128 = 5000*256
    int n = idx >> 7, c = idx & 127;
    h[idx] = emb[x[n] * 128 + c];
}

// ---------------------------------------------------------------------------
// counting-sort phase 1: histogram of dst
__global__ __launch_bounds__(256) void hist_kernel(const int* __restrict__ ei,
                                                   int* __restrict__ counts) {
    int e = blockIdx.x * 256 + threadIdx.x;
    if (e < E_NUM) atomicAdd(&counts[ei[E_NUM + e]], 1);
}

// phase 2: exclusive scan over 10000 bins (single block, 256 threads x 40)
__global__ __launch_bounds__(256) void scan_kernel(const int* __restrict__ counts,
                                                   int* __restrict__ offs,
                                                   int* __restrict__ cursor) {
    __shared__ int part[256];
    const int tid = threadIdx.x;
    const int CH = 40;                 // 256*40 = 10240 >= 10000
    int base = tid * CH;
    int s = 0;
    for (int i = 0; i < CH; ++i) {
        int idx = base + i;
        if (idx < N_NUM) s += counts[idx];
    }
    part[tid] = s;
    __syncthreads();
    for (int off = 1; off < 256; off <<= 1) {
        int v = (tid >= off) ? part[tid - off] : 0;
        __syncthreads();
        part[tid] += v;
        __syncthreads();
    }
    int run = (tid > 0) ? part[tid - 1] : 0;
    for (int i = 0; i < CH; ++i) {
        int idx = base + i;
        if (idx < N_NUM) {
            offs[idx] = run;
            cursor[idx] = run;
            run += counts[idx];
        }
    }
    if (tid == 255) offs[N_NUM] = part[255];
}

// phase 3: scatter edges to dst-sorted order; precompute table index + frac
__global__ __launch_bounds__(256) void scatter_kernel(const int* __restrict__ ei,
                                                      const float* __restrict__ dist,
                                                      int* __restrict__ cursor,
                                                      int* __restrict__ src_s,
                                                      int* __restrict__ i0_s,
                                                      float* __restrict__ fr_s) {
    int e = blockIdx.x * 256 + threadIdx.x;
    if (e >= E_NUM) return;
    int d = ei[E_NUM + e];
    int pos = atomicAdd(&cursor[d], 1);
    src_s[pos] = ei[e];
    float t = dist[e] * ((float)(TAB - 1) / 10.0f);
    int i0 = (int)t;
    if (i0 > TAB - 2) i0 = TAB - 2;
    i0_s[pos] = i0;
    fr_s[pos] = t - (float)i0;
}

// ---------------------------------------------------------------------------
// Build filter tables: tab[l][i][c] = ((ssp(ea(d_i)@w1+b1)@w2)+b2)[c] * C(d_i)
// d_i = i * 10/(TAB-1). 64 rows per block; blockIdx = l*64 + tile.
__global__ __launch_bounds__(256) void table_kernel(const float* __restrict__ mlp_w1,
                                                    const float* __restrict__ mlp_b1,
                                                    const float* __restrict__ mlp_w2,
                                                    const float* __restrict__ mlp_b2,
                                                    float* __restrict__ tab) {
    __shared__ float eaT[50][68];
    __shared__ float hT[128][68];
    const int tid = threadIdx.x;
    const int l = blockIdx.x >> 6;
    const int r0 = (blockIdx.x & 63) * 64;
    const float DG = 10.0f / (float)(TAB - 1);
    const float STEP = 10.0f / 49.0f;
    const float COEFF = -0.5f / (STEP * STEP);
    const float* w1 = mlp_w1 + l * 6400;
    const float* b1 = mlp_b1 + l * 128;
    const float* w2 = mlp_w2 + l * 16384;
    const float* b2 = mlp_b2 + l * 128;

    for (int i = tid; i < 50 * 64; i += 256) {
        int k = i >> 6, e = i & 63;
        float d = (float)(r0 + e) * DG;
        float t = d - (float)k * STEP;
        eaT[k][e] = __expf(COEFF * t * t);
    }
    __syncthreads();

    const int eg = tid & 15;   // rows eg*4 .. +3
    const int jg = tid >> 4;   // cols jg*8 .. +7

    float acc[4][8];
    #pragma unroll
    for (int i = 0; i < 4; ++i)
        #pragma unroll
        for (int j = 0; j < 8; ++j) acc[i][j] = 0.f;
    {
        const float* Bj = w1 + jg * 8;
        #pragma unroll 2
        for (int k = 0; k < 50; ++k) {
            float4 a = *(const float4*)&eaT[k][eg * 4];
            float b[8];
            *(float4*)&b[0] = *(const float4*)(Bj + k * 128);
            *(float4*)&b[4] = *(const float4*)(Bj + k * 128 + 4);
            float av[4] = {a.x, a.y, a.z, a.w};
            #pragma unroll
            for (int i = 0; i < 4; ++i)
                #pragma unroll
                for (int j = 0; j < 8; ++j) acc[i][j] = fmaf(av[i], b[j], acc[i][j]);
        }
    }
    {
        float b1v[8];
        *(float4*)&b1v[0] = *(const float4*)(b1 + jg * 8);
        *(float4*)&b1v[4] = *(const float4*)(b1 + jg * 8 + 4);
        #pragma unroll
        for (int j = 0; j < 8; ++j) {
            float4 v;
            v.x = ssp_f(acc[0][j] + b1v[j]);
            v.y = ssp_f(acc[1][j] + b1v[j]);
            v.z = ssp_f(acc[2][j] + b1v[j]);
            v.w = ssp_f(acc[3][j] + b1v[j]);
            *(float4*)&hT[jg * 8 + j][eg * 4] = v;
        }
    }
    __syncthreads();

    float acc2[4][8];
    #pragma unroll
    for (int i = 0; i < 4; ++i)
        #pragma unroll
        for (int j = 0; j < 8; ++j) acc2[i][j] = 0.f;
    {
        const float* Bj = w2 + jg * 8;
        #pragma unroll 4
        for (int k = 0; k < 128; ++k) {
            float4 a = *(const float4*)&hT[k][eg * 4];
            float b[8];
            *(float4*)&b[0] = *(const float4*)(Bj + k * 128);
            *(float4*)&b[4] = *(const float4*)(Bj + k * 128 + 4);
            float av[4] = {a.x, a.y, a.z, a.w};
            #pragma unroll
            for (int i = 0; i < 4; ++i)
                #pragma unroll
                for (int j = 0; j < 8; ++j) acc2[i][j] = fmaf(av[i], b[j], acc2[i][j]);
        }
    }

    float bv[8];
    *(float4*)&bv[0] = *(const float4*)(b2 + jg * 8);
    *(float4*)&bv[4] = *(const float4*)(b2 + jg * 8 + 4);
    #pragma unroll
    for (int i = 0; i < 4; ++i) {
        int row = r0 + eg * 4 + i;
        float d = (float)row * DG;
        float C = 0.5f * (__cosf(d * 0.31415926535f) + 1.0f);
        float* tr = tab + ((size_t)l * TAB + row) * 128 + jg * 8;
        float o[8];
        #pragma unroll
        for (int j = 0; j < 8; ++j) o[j] = (acc2[i][j] + bv[j]) * C;
        *(float4*)(tr)     = *(float4*)&o[0];
        *(float4*)(tr + 4) = *(float4*)&o[4];
    }
}

// ---------------------------------------------------------------------------
// out[M][128] = A[M][128] @ B[128][128] ; 64 rows/block, 4x8 register blocking
__global__ __launch_bounds__(256) void gemm128(const float* __restrict__ A,
                                               const float* __restrict__ B,
                                               float* __restrict__ out, int M) {
    __shared__ float AT[128][68];
    const int tid = threadIdx.x;
    const int row0 = blockIdx.x * 64;

    for (int i = tid; i < 64 * 128; i += 256) {
        int r = i >> 7, c = i & 127;
        AT[c][r] = (row0 + r < M) ? A[(row0 + r) * 128 + c] : 0.f;
    }
    __syncthreads();

    const int eg = tid & 15;
    const int jg = tid >> 4;
    float acc[4][8];
    #pragma unroll
    for (int i = 0; i < 4; ++i)
        #pragma unroll
        for (int j = 0; j < 8; ++j) acc[i][j] = 0.f;

    const float* Bj = B + jg * 8;
    #pragma unroll 4
    for (int k = 0; k < 128; ++k) {
        float4 a = *(const float4*)&AT[k][eg * 4];
        float b[8];
        *(float4*)&b[0] = *(const float4*)(Bj + k * 128);
        *(float4*)&b[4] = *(const float4*)(Bj + k * 128 + 4);
        float av[4] = {a.x, a.y, a.z, a.w};
        #pragma unroll
        for (int i = 0; i < 4; ++i)
            #pragma unroll
            for (int j = 0; j < 8; ++j) acc[i][j] = fmaf(av[i], b[j], acc[i][j]);
    }

    #pragma unroll
    for (int i = 0; i < 4; ++i) {
        int r = row0 + eg * 4 + i;
        if (r < M) {
            float* orow = out + (size_t)r * 128 + jg * 8;
            *(float4*)(orow)     = *(float4*)&acc[i][0];
            *(float4*)(orow + 4) = *(float4*)&acc[i][4];
        }
    }
}

// ---------------------------------------------------------------------------
// Atomic-free aggregation: one wave per dst node.
// agg[n] = sum over sorted edge segment of xf[src] * lerp(tab, d)
__global__ __launch_bounds__(256) void agg_kernel(const int* __restrict__ offs,
                                                  const int* __restrict__ src_s,
                                                  const int* __restrict__ i0_s,
                                                  const float* __restrict__ fr_s,
                                                  const float* __restrict__ xf,
                                                  const float* __restrict__ tab,
                                                  float* __restrict__ agg) {
    int node = (blockIdx.x * 256 + threadIdx.x) >> 6;
    if (node >= N_NUM) return;
    int lane = threadIdx.x & 63;
    int c = lane * 2;
    int beg = offs[node], end = offs[node + 1];

    float2 acc = {0.f, 0.f};
    int s = 0, i0 = 0; float f = 0.f;
    if (beg < end) { s = src_s[beg]; i0 = i0_s[beg]; f = fr_s[beg]; }
    for (int e = beg; e < end; ++e) {
        int sn = 0, i0n = 0; float fn = 0.f;
        if (e + 1 < end) { sn = src_s[e + 1]; i0n = i0_s[e + 1]; fn = fr_s[e + 1]; }
        float2 xv = *(const float2*)(xf + (size_t)s * 128 + c);
        float2 t0 = *(const float2*)(tab + (size_t)i0 * 128 + c);
        float2 t1 = *(const float2*)(tab + (size_t)(i0 + 1) * 128 + c);
        float w0 = fmaf(f, t1.x - t0.x, t0.x);
        float w1 = fmaf(f, t1.y - t0.y, t0.y);
        acc.x = fmaf(xv.x, w0, acc.x);
        acc.y = fmaf(xv.y, w1, acc.y);
        s = sn; i0 = i0n; f = fn;
    }
    *(float2*)(agg + (size_t)node * 128 + c) = acc;
}

// ---------------------------------------------------------------------------
// h = h + ssp(agg@lin2 + lin2_b)@lin_w + lin_b   (fused two-stage, 64 rows/blk)
__global__ __launch_bounds__(256) void update_kernel(const float* __restrict__ agg,
                                                     const float* __restrict__ lin2_w,
                                                     const float* __restrict__ lin2_b,
                                                     const float* __restrict__ lin_w,
                                                     const float* __restrict__ lin_b,
                                                     float* __restrict__ h, int M) {
    __shared__ float AT[128][68];   // stage1 A (agg), then reused for t
    const int tid = threadIdx.x;
    const int row0 = blockIdx.x * 64;

    for (int i = tid; i < 64 * 128; i += 256) {
        int r = i >> 7, c = i & 127;
        AT[c][r] = (row0 + r < M) ? agg[(row0 + r) * 128 + c] : 0.f;
    }
    __syncthreads();

    const int eg = tid & 15;
    const int jg = tid >> 4;

    float acc[4][8];
    #pragma unroll
    for (int i = 0; i < 4; ++i)
        #pragma unroll
        for (int j = 0; j < 8; ++j) acc[i][j] = 0.f;
    {
        const float* Bj = lin2_w + jg * 8;
        #pragma unroll 4
        for (int k = 0; k < 128; ++k) {
            float4 a = *(const float4*)&AT[k][eg * 4];
            float b[8];
            *(float4*)&b[0] = *(const float4*)(Bj + k * 128);
            *(float4*)&b[4] = *(const float4*)(Bj + k * 128 + 4);
            float av[4] = {a.x, a.y, a.z, a.w};
            #pragma unroll
            for (int i = 0; i < 4; ++i)
                #pragma unroll
                for (int j = 0; j < 8; ++j) acc[i][j] = fmaf(av[i], b[j], acc[i][j]);
        }
    }
    __syncthreads();   // all reads of AT done before overwrite
    {
        float bv[8];
        *(float4*)&bv[0] = *(const float4*)(lin2_b + jg * 8);
        *(float4*)&bv[4] = *(const float4*)(lin2_b + jg * 8 + 4);
        #pragma unroll
        for (int j = 0; j < 8; ++j) {
            float4 v;
            v.x = ssp_f(acc[0][j] + bv[j]);
            v.y = ssp_f(acc[1][j] + bv[j]);
            v.z = ssp_f(acc[2][j] + bv[j]);
            v.w = ssp_f(acc[3][j] + bv[j]);
            *(float4*)&AT[jg * 8 + j][eg * 4] = v;   // t, k-major
        }
    }
    __syncthreads();

    float acc2[4][8];
    #pragma unroll
    for (int i = 0; i < 4; ++i)
        #pragma unroll
        for (int j = 0; j < 8; ++j) acc2[i][j] = 0.f;
    {
        const float* Bj = lin_w + jg * 8;
        #pragma unroll 4
        for (int k = 0; k < 128; ++k) {
            float4 a = *(const float4*)&AT[k][eg * 4];
            float b[8];
            *(float4*)&b[0] = *(const float4*)(Bj + k * 128);
            *(float4*)&b[4] = *(const float4*)(Bj + k * 128 + 4);
            float av[4] = {a.x, a.y, a.z, a.w};
            #pragma unroll
            for (int i = 0; i < 4; ++i)
                #pragma unroll
                for (int j = 0; j < 8; ++j) acc2[i][j] = fmaf(av[i], b[j], acc2[i][j]);
        }
    }

    float bv[8];
    *(float4*)&bv[0] = *(const float4*)(lin_b + jg * 8);
    *(float4*)&bv[4] = *(const float4*)(lin_b + jg * 8 + 4);
    #pragma unroll
    for (int i = 0; i < 4; ++i) {
        int r = row0 + eg * 4 + i;
        if (r < M) {
            float* hr = h + (size_t)r * 128 + jg * 8;
            float4 h0 = *(const float4*)(hr);
            float4 h1 = *(const float4*)(hr + 4);
            float o[8];
            o[0] = h0.x + acc2[i][0] + bv[0];
            o[1] = h0.y + acc2[i][1] + bv[1];
            o[2] = h0.z + acc2[i][2] + bv[2];
            o[3] = h0.w + acc2[i][3] + bv[3];
            o[4] = h1.x + acc2[i][4] + bv[4];
            o[5] = h1.y + acc2[i][5] + bv[5];
            o[6] = h1.z + acc2[i][6] + bv[6];
            o[7] = h1.w + acc2[i][7] + bv[7];
            *(float4*)(hr)     = *(float4*)&o[0];
            *(float4*)(hr + 4) = *(float4*)&o[4];
        }
    }
}

// ---------------------------------------------------------------------------
// head: t = ssp(h@w1+b1); t = t@w2+b2; gs += colsum(t)   (gs: [64])
__global__ __launch_bounds__(256) void head_kernel(const float* __restrict__ h,
                                                   const float* __restrict__ w1,
                                                   const float* __restrict__ b1,
                                                   const float* __restrict__ w2,
                                                   const float* __restrict__ b2,
                                                   float* __restrict__ gs, int M) {
    __shared__ float hT[128][68];
    __shared__ float t1T[64][68];
    __shared__ float red[16][64];
    const int tid = threadIdx.x;
    const int row0 = blockIdx.x * 64;

    for (int i = tid; i < 64 * 128; i += 256) {
        int r = i >> 7, c = i & 127;
        hT[c][r] = (row0 + r < M) ? h[(row0 + r) * 128 + c] : 0.f;
    }
    __syncthreads();

    const int rg = tid & 15;
    const int cg = tid >> 4;

    float acc[4][4];
    #pragma unroll
    for (int i = 0; i < 4; ++i)
        #pragma unroll
        for (int j = 0; j < 4; ++j) acc[i][j] = 0.f;
    #pragma unroll 4
    for (int k = 0; k < 128; ++k) {
        float4 a = *(const float4*)&hT[k][rg * 4];
        float4 b = *(const float4*)(w1 + k * 64 + cg * 4);
        float av[4] = {a.x, a.y, a.z, a.w};
        float bb[4] = {b.x, b.y, b.z, b.w};
        #pragma unroll
        for (int i = 0; i < 4; ++i)
            #pragma unroll
            for (int j = 0; j < 4; ++j) acc[i][j] = fmaf(av[i], bb[j], acc[i][j]);
    }
    {
        float4 b1v = *(const float4*)(b1 + cg * 4);
        float bb[4] = {b1v.x, b1v.y, b1v.z, b1v.w};
        #pragma unroll
        for (int j = 0; j < 4; ++j) {
            float4 v;
            v.x = ssp_f(acc[0][j] + bb[j]);
            v.y = ssp_f(acc[1][j] + bb[j]);
            v.z = ssp_f(acc[2][j] + bb[j]);
            v.w = ssp_f(acc[3][j] + bb[j]);
            *(float4*)&t1T[cg * 4 + j][rg * 4] = v;
        }
    }
    __syncthreads();

    float acc2[4][4];
    #pragma unroll
    for (int i = 0; i < 4; ++i)
        #pragma unroll
        for (int j = 0; j < 4; ++j) acc2[i][j] = 0.f;
    #pragma unroll 4
    for (int k = 0; k < 64; ++k) {
        float4 a = *(const float4*)&t1T[k][rg * 4];
        float4 b = *(const float4*)(w2 + k * 64 + cg * 4);
        float av[4] = {a.x, a.y, a.z, a.w};
        float bb[4] = {b.x, b.y, b.z, b.w};
        #pragma unroll
        for (int i = 0; i < 4; ++i)
            #pragma unroll
            for (int j = 0; j < 4; ++j) acc2[i][j] = fmaf(av[i], bb[j], acc2[i][j]);
    }
    {
        float4 b2v = *(const float4*)(b2 + cg * 4);
        float bb[4] = {b2v.x, b2v.y, b2v.z, b2v.w};
        float cs[4] = {0.f, 0.f, 0.f, 0.f};
        #pragma unroll
        for (int i = 0; i < 4; ++i) {
            if (row0 + rg * 4 + i < M) {
                #pragma unroll
                for (int j = 0; j < 4; ++j) cs[j] += acc2[i][j] + bb[j];
            }
        }
        #pragma unroll
        for (int j = 0; j < 4; ++j) red[rg][cg * 4 + j] = cs[j];
    }
    __syncthreads();
    if (tid < 64) {
        float s = 0.f;
        #pragma unroll
        for (int r = 0; r < 16; ++r) s += red[r][tid];
        atomicAdd(&gs[tid], s);
    }
}

// out[i] = ro_b[i] + sum_k gs[k] * ro_w[k][i]
__global__ void final_kernel(const float* __restrict__ gs,
                             const float* __restrict__ ro_w,
                             const float* __restrict__ ro_b,
                             float* __restrict__ out) {
    int i = threadIdx.x;
    if (i < 12) {
        float s = ro_b[i];
        for (int k = 0; k < 64; ++k) s = fmaf(gs[k], ro_w[k * 12 + i], s);
        out[i] = s;
    }
}

// ---------------------------------------------------------------------------
extern "C" void kernel_launch(void* const* d_in, const int* in_sizes, int n_in,
                              void* d_out, int out_size, void* d_ws, size_t ws_size,
                              hipStream_t stream) {
    const int*   x      = (const int*)d_in[0];
    const int*   ei     = (const int*)d_in[1];
    const float* dist   = (const float*)d_in[2];
    const float* emb    = (const float*)d_in[3];
    const float* mlp_w1 = (const float*)d_in[4];
    const float* mlp_b1 = (const float*)d_in[5];
    const float* mlp_w2 = (const float*)d_in[6];
    const float* mlp_b2 = (const float*)d_in[7];
    const float* lin1_w = (const float*)d_in[8];
    const float* lin2_w = (const float*)d_in[9];
    const float* lin2_b = (const float*)d_in[10];
    const float* lin_w  = (const float*)d_in[11];
    const float* lin_b  = (const float*)d_in[12];
    const float* out1_w = (const float*)d_in[13];
    const float* out1_b = (const float*)d_in[14];
    const float* out2_w = (const float*)d_in[15];
    const float* out2_b = (const float*)d_in[16];
    const float* ro_w   = (const float*)d_in[17];
    const float* ro_b   = (const float*)d_in[18];
    float* out = (float*)d_out;

    // workspace layout
    float* h      = (float*)d_ws;                    // N*128
    float* xf     = h + N_NUM * 128;                 // N*128
    float* agg    = xf + N_NUM * 128;                // N*128
    float* tab    = agg + N_NUM * 128;               // 6*TAB*128
    float* fr_s   = tab + 6 * TAB * 128;             // E
    float* gs     = fr_s + E_NUM;                    // 64
    int*   src_s  = (int*)(gs + 64);                 // E
    int*   i0_s   = src_s + E_NUM;                   // E
    int*   offs   = i0_s + E_NUM;                    // N+1
    int*   cursor = offs + N_NUM + 1;                // N
    int*   counts = cursor + N_NUM;                  // N

    hipMemsetAsync(counts, 0, N_NUM * sizeof(int), stream);
    hipMemsetAsync(gs, 0, 64 * sizeof(float), stream);

    embed_kernel<<<N_NUM * 128 / 256, 256, 0, stream>>>(x, emb, h);

    // sort edges by dst (once; dst constant across layers)
    hist_kernel<<<(E_NUM + 255) / 256, 256, 0, stream>>>(ei, counts);
    scan_kernel<<<1, 256, 0, stream>>>(counts, offs, cursor);
    scatter_kernel<<<(E_NUM + 255) / 256, 256, 0, stream>>>(ei, dist, cursor,
                                                            src_s, i0_s, fr_s);

    // build all 6 layer filter tables
    table_kernel<<<6 * (TAB / 64), 256, 0, stream>>>(mlp_w1, mlp_b1, mlp_w2,
                                                     mlp_b2, tab);

    for (int l = 0; l < 6; ++l) {
        gemm128<<<NBLK, 256, 0, stream>>>(h, lin1_w + l * 16384, xf, N_NUM);
        agg_kernel<<<(N_NUM + 3) / 4, 256, 0, stream>>>(
            offs, src_s, i0_s, fr_s, xf, tab + (size_t)l * TAB * 128, agg);
        update_kernel<<<NBLK, 256, 0, stream>>>(
            agg, lin2_w + l * 16384, lin2_b + l * 128,
            lin_w + l * 16384, lin_b + l * 128, h, N_NUM);
    }

    head_kernel<<<NBLK, 256, 0, stream>>>(h, out1_w, out1_b, out2_w, out2_b, gs, N_NUM);
    final_kernel<<<1, 64, 0, stream>>>(gs, ro_w, ro_b, out);
}

// Round 3
// 840.283 us; speedup vs baseline: 8.9143x; 1.0977x over previous
//
#include <hip/hip_runtime.h>
#include <math.h>

#define E_NUM 320000
#define N_NUM 10000
#define NBLK  ((N_NUM + 63) / 64)   // 157
#define TAB   2048
#define AGG_BLOCKS 512

__device__ __forceinline__ float ssp_f(float x) {
    // softplus(x) - log(2), stable: max(x,0) + log(1+exp(-|x|)) - log2
    return fmaxf(x, 0.f) + __logf(1.f + __expf(-fabsf(x))) - 0.69314718056f;
}

// ---------------------------------------------------------------------------
// counting-sort phase 1: histogram of dst
__global__ __launch_bounds__(256) void hist_kernel(const int* __restrict__ ei,
                                                   int* __restrict__ counts) {
    int e = blockIdx.x * 256 + threadIdx.x;
    if (e < E_NUM) atomicAdd(&counts[ei[E_NUM + e]], 1);
}

// phase 2: exclusive scan over 10000 bins (single block, 256 threads x 40)
__global__ __launch_bounds__(256) void scan_kernel(const int* __restrict__ counts,
                                                   int* __restrict__ offs,
                                                   int* __restrict__ cursor) {
    __shared__ int part[256];
    const int tid = threadIdx.x;
    const int CH = 40;                 // 256*40 = 10240 >= 10000
    int base = tid * CH;
    int s = 0;
    for (int i = 0; i < CH; ++i) {
        int idx = base + i;
        if (idx < N_NUM) s += counts[idx];
    }
    part[tid] = s;
    __syncthreads();
    for (int off = 1; off < 256; off <<= 1) {
        int v = (tid >= off) ? part[tid - off] : 0;
        __syncthreads();
        part[tid] += v;
        __syncthreads();
    }
    int run = (tid > 0) ? part[tid - 1] : 0;
    for (int i = 0; i < CH; ++i) {
        int idx = base + i;
        if (idx < N_NUM) {
            offs[idx] = run;
            cursor[idx] = run;
            run += counts[idx];
        }
    }
    if (tid == 255) offs[N_NUM] = part[255];
}

// phase 3: scatter edges to dst-sorted order; precompute table index + frac
__global__ __launch_bounds__(256) void scatter_kernel(const int* __restrict__ ei,
                                                      const float* __restrict__ dist,
                                                      int* __restrict__ cursor,
                                                      int* __restrict__ src_s,
                                                      int* __restrict__ i0_s,
                                                      float* __restrict__ fr_s) {
    int e = blockIdx.x * 256 + threadIdx.x;
    if (e >= E_NUM) return;
    int d = ei[E_NUM + e];
    int pos = atomicAdd(&cursor[d], 1);
    src_s[pos] = ei[e];
    float t = dist[e] * ((float)(TAB - 1) / 10.0f);
    int i0 = (int)t;
    if (i0 > TAB - 2) i0 = TAB - 2;
    i0_s[pos] = i0;
    fr_s[pos] = t - (float)i0;
}

// ---------------------------------------------------------------------------
// Build filter tables: tab[l][i][c] = ((ssp(ea(d_i)@w1+b1)@w2)+b2)[c] * C(d_i)
// d_i = i * 10/(TAB-1). 64 rows per block; blockIdx = l*(TAB/64) + tile.
__global__ __launch_bounds__(256) void table_kernel(const float* __restrict__ mlp_w1,
                                                    const float* __restrict__ mlp_b1,
                                                    const float* __restrict__ mlp_w2,
                                                    const float* __restrict__ mlp_b2,
                                                    float* __restrict__ tab) {
    __shared__ float eaT[50][68];
    __shared__ float hT[128][68];
    const int tid = threadIdx.x;
    const int l = blockIdx.x / (TAB / 64);
    const int r0 = (blockIdx.x % (TAB / 64)) * 64;
    const float DG = 10.0f / (float)(TAB - 1);
    const float STEP = 10.0f / 49.0f;
    const float COEFF = -0.5f / (STEP * STEP);
    const float* w1 = mlp_w1 + l * 6400;
    const float* b1 = mlp_b1 + l * 128;
    const float* w2 = mlp_w2 + l * 16384;
    const float* b2 = mlp_b2 + l * 128;

    for (int i = tid; i < 50 * 64; i += 256) {
        int k = i >> 6, e = i & 63;
        float d = (float)(r0 + e) * DG;
        float t = d - (float)k * STEP;
        eaT[k][e] = __expf(COEFF * t * t);
    }
    __syncthreads();

    const int eg = tid & 15;   // rows eg*4 .. +3
    const int jg = tid >> 4;   // cols jg*8 .. +7

    float acc[4][8];
    #pragma unroll
    for (int i = 0; i < 4; ++i)
        #pragma unroll
        for (int j = 0; j < 8; ++j) acc[i][j] = 0.f;
    {
        const float* Bj = w1 + jg * 8;
        #pragma unroll 2
        for (int k = 0; k < 50; ++k) {
            float4 a = *(const float4*)&eaT[k][eg * 4];
            float b[8];
            *(float4*)&b[0] = *(const float4*)(Bj + k * 128);
            *(float4*)&b[4] = *(const float4*)(Bj + k * 128 + 4);
            float av[4] = {a.x, a.y, a.z, a.w};
            #pragma unroll
            for (int i = 0; i < 4; ++i)
                #pragma unroll
                for (int j = 0; j < 8; ++j) acc[i][j] = fmaf(av[i], b[j], acc[i][j]);
        }
    }
    {
        float b1v[8];
        *(float4*)&b1v[0] = *(const float4*)(b1 + jg * 8);
        *(float4*)&b1v[4] = *(const float4*)(b1 + jg * 8 + 4);
        #pragma unroll
        for (int j = 0; j < 8; ++j) {
            float4 v;
            v.x = ssp_f(acc[0][j] + b1v[j]);
            v.y = ssp_f(acc[1][j] + b1v[j]);
            v.z = ssp_f(acc[2][j] + b1v[j]);
            v.w = ssp_f(acc[3][j] + b1v[j]);
            *(float4*)&hT[jg * 8 + j][eg * 4] = v;
        }
    }
    __syncthreads();

    float acc2[4][8];
    #pragma unroll
    for (int i = 0; i < 4; ++i)
        #pragma unroll
        for (int j = 0; j < 8; ++j) acc2[i][j] = 0.f;
    {
        const float* Bj = w2 + jg * 8;
        #pragma unroll 4
        for (int k = 0; k < 128; ++k) {
            float4 a = *(const float4*)&hT[k][eg * 4];
            float b[8];
            *(float4*)&b[0] = *(const float4*)(Bj + k * 128);
            *(float4*)&b[4] = *(const float4*)(Bj + k * 128 + 4);
            float av[4] = {a.x, a.y, a.z, a.w};
            #pragma unroll
            for (int i = 0; i < 4; ++i)
                #pragma unroll
                for (int j = 0; j < 8; ++j) acc2[i][j] = fmaf(av[i], b[j], acc2[i][j]);
        }
    }

    float bv[8];
    *(float4*)&bv[0] = *(const float4*)(b2 + jg * 8);
    *(float4*)&bv[4] = *(const float4*)(b2 + jg * 8 + 4);
    #pragma unroll
    for (int i = 0; i < 4; ++i) {
        int row = r0 + eg * 4 + i;
        float d = (float)row * DG;
        float C = 0.5f * (__cosf(d * 0.31415926535f) + 1.0f);
        float* tr = tab + ((size_t)l * TAB + row) * 128 + jg * 8;
        float o[8];
        #pragma unroll
        for (int j = 0; j < 8; ++j) o[j] = (acc2[i][j] + bv[j]) * C;
        *(float4*)(tr)     = *(float4*)&o[0];
        *(float4*)(tr + 4) = *(float4*)&o[4];
    }
}

// ---------------------------------------------------------------------------
// Layer 0 front: h = emb[x]; xf = h @ lin1_w[0]
__global__ __launch_bounds__(256) void embed_lin1_kernel(const int* __restrict__ x,
                                                         const float* __restrict__ emb,
                                                         const float* __restrict__ B,
                                                         float* __restrict__ h,
                                                         float* __restrict__ xf, int M) {
    __shared__ float AT[128][68];
    __shared__ int s_x[64];
    const int tid = threadIdx.x;
    const int row0 = blockIdx.x * 64;

    if (tid < 64) s_x[tid] = (row0 + tid < M) ? x[row0 + tid] : 0;
    __syncthreads();
    for (int i = tid; i < 64 * 128; i += 256) {
        int r = i >> 7, c = i & 127;
        float v = (row0 + r < M) ? emb[s_x[r] * 128 + c] : 0.f;
        AT[c][r] = v;
        if (row0 + r < M) h[(size_t)(row0 + r) * 128 + c] = v;
    }
    __syncthreads();

    const int eg = tid & 15;
    const int jg = tid >> 4;
    float acc[4][8];
    #pragma unroll
    for (int i = 0; i < 4; ++i)
        #pragma unroll
        for (int j = 0; j < 8; ++j) acc[i][j] = 0.f;

    const float* Bj = B + jg * 8;
    #pragma unroll 4
    for (int k = 0; k < 128; ++k) {
        float4 a = *(const float4*)&AT[k][eg * 4];
        float b[8];
        *(float4*)&b[0] = *(const float4*)(Bj + k * 128);
        *(float4*)&b[4] = *(const float4*)(Bj + k * 128 + 4);
        float av[4] = {a.x, a.y, a.z, a.w};
        #pragma unroll
        for (int i = 0; i < 4; ++i)
            #pragma unroll
            for (int j = 0; j < 8; ++j) acc[i][j] = fmaf(av[i], b[j], acc[i][j]);
    }

    #pragma unroll
    for (int i = 0; i < 4; ++i) {
        int r = row0 + eg * 4 + i;
        if (r < M) {
            float* orow = xf + (size_t)r * 128 + jg * 8;
            *(float4*)(orow)     = *(float4*)&acc[i][0];
            *(float4*)(orow + 4) = *(float4*)&acc[i][4];
        }
    }
}

// ---------------------------------------------------------------------------
// Atomic-free aggregation, persistent waves, 4x-unrolled edge loop.
// agg[n] = sum over sorted edge segment of xf[src] * lerp(tab, d)
__global__ __launch_bounds__(256) void agg_kernel(const int* __restrict__ offs,
                                                  const int* __restrict__ src_s,
                                                  const int* __restrict__ i0_s,
                                                  const float* __restrict__ fr_s,
                                                  const float* __restrict__ xf,
                                                  const float* __restrict__ tab,
                                                  float* __restrict__ agg) {
    const int wid0 = blockIdx.x * 4 + (threadIdx.x >> 6);
    const int lane = threadIdx.x & 63;
    const int c = lane * 2;
    const int stride = AGG_BLOCKS * 4;

    for (int node = wid0; node < N_NUM; node += stride) {
        int beg = offs[node], end = offs[node + 1];
        float2 accA = {0.f, 0.f}, accB = {0.f, 0.f};
        int e = beg;
        for (; e + 4 <= end; e += 4) {
            int   s[4], i0[4];
            float f[4];
            #pragma unroll
            for (int u = 0; u < 4; ++u) {
                s[u]  = src_s[e + u];
                i0[u] = i0_s[e + u];
                f[u]  = fr_s[e + u];
            }
            float2 xv[4], t0[4], t1[4];
            #pragma unroll
            for (int u = 0; u < 4; ++u) {
                xv[u] = *(const float2*)(xf  + (size_t)s[u] * 128 + c);
                t0[u] = *(const float2*)(tab + (size_t)i0[u] * 128 + c);
                t1[u] = *(const float2*)(tab + (size_t)(i0[u] + 1) * 128 + c);
            }
            #pragma unroll
            for (int u = 0; u < 4; ++u) {
                float w0 = fmaf(f[u], t1[u].x - t0[u].x, t0[u].x);
                float w1 = fmaf(f[u], t1[u].y - t0[u].y, t0[u].y);
                if (u & 1) {
                    accB.x = fmaf(xv[u].x, w0, accB.x);
                    accB.y = fmaf(xv[u].y, w1, accB.y);
                } else {
                    accA.x = fmaf(xv[u].x, w0, accA.x);
                    accA.y = fmaf(xv[u].y, w1, accA.y);
                }
            }
        }
        for (; e < end; ++e) {
            int   s  = src_s[e];
            int   i0 = i0_s[e];
            float f  = fr_s[e];
            float2 xv = *(const float2*)(xf  + (size_t)s * 128 + c);
            float2 t0 = *(const float2*)(tab + (size_t)i0 * 128 + c);
            float2 t1 = *(const float2*)(tab + (size_t)(i0 + 1) * 128 + c);
            float w0 = fmaf(f, t1.x - t0.x, t0.x);
            float w1 = fmaf(f, t1.y - t0.y, t0.y);
            accA.x = fmaf(xv.x, w0, accA.x);
            accA.y = fmaf(xv.y, w1, accA.y);
        }
        float2 o = {accA.x + accB.x, accA.y + accB.y};
        *(float2*)(agg + (size_t)node * 128 + c) = o;
    }
}

// ---------------------------------------------------------------------------
// Fused per-layer node update (3 chained GEMMs through one LDS tile):
//   conv  = agg @ lin2_w + lin2_b
//   h_new = h + ssp(conv) @ lin_w + lin_b
//   xf    = h_new @ lin1_next           (skipped when LAST)
template <bool LAST>
__global__ __launch_bounds__(256) void update_kernel(const float* __restrict__ agg,
                                                     const float* __restrict__ lin2_w,
                                                     const float* __restrict__ lin2_b,
                                                     const float* __restrict__ lin_w,
                                                     const float* __restrict__ lin_b,
                                                     const float* __restrict__ lin1_next,
                                                     float* __restrict__ h,
                                                     float* __restrict__ xf, int M) {
    __shared__ float AT[128][68];   // agg -> t -> h_new (k-major), reused
    const int tid = threadIdx.x;
    const int row0 = blockIdx.x * 64;

    for (int i = tid; i < 64 * 128; i += 256) {
        int r = i >> 7, c = i & 127;
        AT[c][r] = (row0 + r < M) ? agg[(size_t)(row0 + r) * 128 + c] : 0.f;
    }
    __syncthreads();

    const int eg = tid & 15;
    const int jg = tid >> 4;

    // stage 1: conv = agg @ lin2_w
    float acc[4][8];
    #pragma unroll
    for (int i = 0; i < 4; ++i)
        #pragma unroll
        for (int j = 0; j < 8; ++j) acc[i][j] = 0.f;
    {
        const float* Bj = lin2_w + jg * 8;
        #pragma unroll 4
        for (int k = 0; k < 128; ++k) {
            float4 a = *(const float4*)&AT[k][eg * 4];
            float b[8];
            *(float4*)&b[0] = *(const float4*)(Bj + k * 128);
            *(float4*)&b[4] = *(const float4*)(Bj + k * 128 + 4);
            float av[4] = {a.x, a.y, a.z, a.w};
            #pragma unroll
            for (int i = 0; i < 4; ++i)
                #pragma unroll
                for (int j = 0; j < 8; ++j) acc[i][j] = fmaf(av[i], b[j], acc[i][j]);
        }
    }
    __syncthreads();   // all reads of AT done before overwrite
    {
        float bv[8];
        *(float4*)&bv[0] = *(const float4*)(lin2_b + jg * 8);
        *(float4*)&bv[4] = *(const float4*)(lin2_b + jg * 8 + 4);
        #pragma unroll
        for (int j = 0; j < 8; ++j) {
            float4 v;
            v.x = ssp_f(acc[0][j] + bv[j]);
            v.y = ssp_f(acc[1][j] + bv[j]);
            v.z = ssp_f(acc[2][j] + bv[j]);
            v.w = ssp_f(acc[3][j] + bv[j]);
            *(float4*)&AT[jg * 8 + j][eg * 4] = v;   // t, k-major
        }
    }
    __syncthreads();

    // stage 2: upd = t @ lin_w ; h_new = h + upd + lin_b
    float acc2[4][8];
    #pragma unroll
    for (int i = 0; i < 4; ++i)
        #pragma unroll
        for (int j = 0; j < 8; ++j) acc2[i][j] = 0.f;
    {
        const float* Bj = lin_w + jg * 8;
        #pragma unroll 4
        for (int k = 0; k < 128; ++k) {
            float4 a = *(const float4*)&AT[k][eg * 4];
            float b[8];
            *(float4*)&b[0] = *(const float4*)(Bj + k * 128);
            *(float4*)&b[4] = *(const float4*)(Bj + k * 128 + 4);
            float av[4] = {a.x, a.y, a.z, a.w};
            #pragma unroll
            for (int i = 0; i < 4; ++i)
                #pragma unroll
                for (int j = 0; j < 8; ++j) acc2[i][j] = fmaf(av[i], b[j], acc2[i][j]);
        }
    }
    __syncthreads();   // stage-2 reads done before overwrite with h_new

    {
        float bv[8];
        *(float4*)&bv[0] = *(const float4*)(lin_b + jg * 8);
        *(float4*)&bv[4] = *(const float4*)(lin_b + jg * 8 + 4);
        #pragma unroll
        for (int i = 0; i < 4; ++i) {
            int r = row0 + eg * 4 + i;
            float hn[8];
            if (r < M) {
                float* hr = h + (size_t)r * 128 + jg * 8;
                float4 h0 = *(const float4*)(hr);
                float4 h1 = *(const float4*)(hr + 4);
                hn[0] = h0.x + acc2[i][0] + bv[0];
                hn[1] = h0.y + acc2[i][1] + bv[1];
                hn[2] = h0.z + acc2[i][2] + bv[2];
                hn[3] = h0.w + acc2[i][3] + bv[3];
                hn[4] = h1.x + acc2[i][4] + bv[4];
                hn[5] = h1.y + acc2[i][5] + bv[5];
                hn[6] = h1.z + acc2[i][6] + bv[6];
                hn[7] = h1.w + acc2[i][7] + bv[7];
                *(float4*)(hr)     = *(float4*)&hn[0];
                *(float4*)(hr + 4) = *(float4*)&hn[4];
            } else {
                #pragma unroll
                for (int j = 0; j < 8; ++j) hn[j] = 0.f;
            }
            if (!LAST) {
                #pragma unroll
                for (int j = 0; j < 8; ++j) AT[jg * 8 + j][eg * 4 + i] = hn[j];
            }
        }
    }
    if (LAST) return;
    __syncthreads();

    // stage 3: xf = h_new @ lin1_next
    float acc3[4][8];
    #pragma unroll
    for (int i = 0; i < 4; ++i)
        #pragma unroll
        for (int j = 0; j < 8; ++j) acc3[i][j] = 0.f;
    {
        const float* Bj = lin1_next + jg * 8;
        #pragma unroll 4
        for (int k = 0; k < 128; ++k) {
            float4 a = *(const float4*)&AT[k][eg * 4];
            float b[8];
            *(float4*)&b[0] = *(const float4*)(Bj + k * 128);
            *(float4*)&b[4] = *(const float4*)(Bj + k * 128 + 4);
            float av[4] = {a.x, a.y, a.z, a.w};
            #pragma unroll
            for (int i = 0; i < 4; ++i)
                #pragma unroll
                for (int j = 0; j < 8; ++j) acc3[i][j] = fmaf(av[i], b[j], acc3[i][j]);
        }
    }
    #pragma unroll
    for (int i = 0; i < 4; ++i) {
        int r = row0 + eg * 4 + i;
        if (r < M) {
            float* orow = xf + (size_t)r * 128 + jg * 8;
            *(float4*)(orow)     = *(float4*)&acc3[i][0];
            *(float4*)(orow + 4) = *(float4*)&acc3[i][4];
        }
    }
}

// ---------------------------------------------------------------------------
// head: t = ssp(h@w1+b1); t = t@w2+b2; gs += colsum(t)   (gs: [64])
__global__ __launch_bounds__(256) void head_kernel(const float* __restrict__ h,
                                                   const float* __restrict__ w1,
                                                   const float* __restrict__ b1,
                                                   const float* __restrict__ w2,
                                                   const float* __restrict__ b2,
                                                   float* __restrict__ gs, int M) {
    __shared__ float hT[128][68];
    __shared__ float t1T[64][68];
    __shared__ float red[16][64];
    const int tid = threadIdx.x;
    const int row0 = blockIdx.x * 64;

    for (int i = tid; i < 64 * 128; i += 256) {
        int r = i >> 7, c = i & 127;
        hT[c][r] = (row0 + r < M) ? h[(row0 + r) * 128 + c] : 0.f;
    }
    __syncthreads();

    const int rg = tid & 15;
    const int cg = tid >> 4;

    float acc[4][4];
    #pragma unroll
    for (int i = 0; i < 4; ++i)
        #pragma unroll
        for (int j = 0; j < 4; ++j) acc[i][j] = 0.f;
    #pragma unroll 4
    for (int k = 0; k < 128; ++k) {
        float4 a = *(const float4*)&hT[k][rg * 4];
        float4 b = *(const float4*)(w1 + k * 64 + cg * 4);
        float av[4] = {a.x, a.y, a.z, a.w};
        float bb[4] = {b.x, b.y, b.z, b.w};
        #pragma unroll
        for (int i = 0; i < 4; ++i)
            #pragma unroll
            for (int j = 0; j < 4; ++j) acc[i][j] = fmaf(av[i], bb[j], acc[i][j]);
    }
    {
        float4 b1v = *(const float4*)(b1 + cg * 4);
        float bb[4] = {b1v.x, b1v.y, b1v.z, b1v.w};
        #pragma unroll
        for (int j = 0; j < 4; ++j) {
            float4 v;
            v.x = ssp_f(acc[0][j] + bb[j]);
            v.y = ssp_f(acc[1][j] + bb[j]);
            v.z = ssp_f(acc[2][j] + bb[j]);
            v.w = ssp_f(acc[3][j] + bb[j]);
            *(float4*)&t1T[cg * 4 + j][rg * 4] = v;
        }
    }
    __syncthreads();

    float acc2[4][4];
    #pragma unroll
    for (int i = 0; i < 4; ++i)
        #pragma unroll
        for (int j = 0; j < 4; ++j) acc2[i][j] = 0.f;
    #pragma unroll 4
    for (int k = 0; k < 64; ++k) {
        float4 a = *(const float4*)&t1T[k][rg * 4];
        float4 b = *(const float4*)(w2 + k * 64 + cg * 4);
        float av[4] = {a.x, a.y, a.z, a.w};
        float bb[4] = {b.x, b.y, b.z, b.w};
        #pragma unroll
        for (int i = 0; i < 4; ++i)
            #pragma unroll
            for (int j = 0; j < 4; ++j) acc2[i][j] = fmaf(av[i], bb[j], acc2[i][j]);
    }
    {
        float4 b2v = *(const float4*)(b2 + cg * 4);
        float bb[4] = {b2v.x, b2v.y, b2v.z, b2v.w};
        float cs[4] = {0.f, 0.f, 0.f, 0.f};
        #pragma unroll
        for (int i = 0; i < 4; ++i) {
            if (row0 + rg * 4 + i < M) {
                #pragma unroll
                for (int j = 0; j < 4; ++j) cs[j] += acc2[i][j] + bb[j];
            }
        }
        #pragma unroll
        for (int j = 0; j < 4; ++j) red[rg][cg * 4 + j] = cs[j];
    }
    __syncthreads();
    if (tid < 64) {
        float s = 0.f;
        #pragma unroll
        for (int r = 0; r < 16; ++r) s += red[r][tid];
        atomicAdd(&gs[tid], s);
    }
}

// out[i] = ro_b[i] + sum_k gs[k] * ro_w[k][i]
__global__ void final_kernel(const float* __restrict__ gs,
                             const float* __restrict__ ro_w,
                             const float* __restrict__ ro_b,
                             float* __restrict__ out) {
    int i = threadIdx.x;
    if (i < 12) {
        float s = ro_b[i];
        for (int k = 0; k < 64; ++k) s = fmaf(gs[k], ro_w[k * 12 + i], s);
        out[i] = s;
    }
}

// ---------------------------------------------------------------------------
extern "C" void kernel_launch(void* const* d_in, const int* in_sizes, int n_in,
                              void* d_out, int out_size, void* d_ws, size_t ws_size,
                              hipStream_t stream) {
    const int*   x      = (const int*)d_in[0];
    const int*   ei     = (const int*)d_in[1];
    const float* dist   = (const float*)d_in[2];
    const float* emb    = (const float*)d_in[3];
    const float* mlp_w1 = (const float*)d_in[4];
    const float* mlp_b1 = (const float*)d_in[5];
    const float* mlp_w2 = (const float*)d_in[6];
    const float* mlp_b2 = (const float*)d_in[7];
    const float* lin1_w = (const float*)d_in[8];
    const float* lin2_w = (const float*)d_in[9];
    const float* lin2_b = (const float*)d_in[10];
    const float* lin_w  = (const float*)d_in[11];
    const float* lin_b  = (const float*)d_in[12];
    const float* out1_w = (const float*)d_in[13];
    const float* out1_b = (const float*)d_in[14];
    const float* out2_w = (const float*)d_in[15];
    const float* out2_b = (const float*)d_in[16];
    const float* ro_w   = (const float*)d_in[17];
    const float* ro_b   = (const float*)d_in[18];
    float* out = (float*)d_out;

    // workspace layout
    float* h      = (float*)d_ws;                    // N*128
    float* xf     = h + N_NUM * 128;                 // N*128
    float* agg    = xf + N_NUM * 128;                // N*128
    float* tab    = agg + N_NUM * 128;               // 6*TAB*128
    float* fr_s   = tab + 6 * TAB * 128;             // E
    float* gs     = fr_s + E_NUM;                    // 64
    int*   src_s  = (int*)(gs + 64);                 // E
    int*   i0_s   = src_s + E_NUM;                   // E
    int*   offs   = i0_s + E_NUM;                    // N+1
    int*   cursor = offs + N_NUM + 1;                // N
    int*   counts = cursor + N_NUM;                  // N

    hipMemsetAsync(counts, 0, N_NUM * sizeof(int), stream);
    hipMemsetAsync(gs, 0, 64 * sizeof(float), stream);

    // sort edges by dst (once; dst constant across layers)
    hist_kernel<<<(E_NUM + 255) / 256, 256, 0, stream>>>(ei, counts);
    scan_kernel<<<1, 256, 0, stream>>>(counts, offs, cursor);
    scatter_kernel<<<(E_NUM + 255) / 256, 256, 0, stream>>>(ei, dist, cursor,
                                                            src_s, i0_s, fr_s);

    // build all 6 layer filter tables
    table_kernel<<<6 * (TAB / 64), 256, 0, stream>>>(mlp_w1, mlp_b1, mlp_w2,
                                                     mlp_b2, tab);

    // layer 0 front: h = emb[x], xf = h @ lin1_w[0]
    embed_lin1_kernel<<<NBLK, 256, 0, stream>>>(x, emb, lin1_w, h, xf, N_NUM);

    for (int l = 0; l < 6; ++l) {
        agg_kernel<<<AGG_BLOCKS, 256, 0, stream>>>(
            offs, src_s, i0_s, fr_s, xf, tab + (size_t)l * TAB * 128, agg);
        if (l < 5) {
            update_kernel<false><<<NBLK, 256, 0, stream>>>(
                agg, lin2_w + l * 16384, lin2_b + l * 128,
                lin_w + l * 16384, lin_b + l * 128,
                lin1_w + (l + 1) * 16384, h, xf, N_NUM);
        } else {
            update_kernel<true><<<NBLK, 256, 0, stream>>>(
                agg, lin2_w + l * 16384, lin2_b + l * 128,
                lin_w + l * 16384, lin_b + l * 128,
                nullptr, h, xf, N_NUM);
        }
    }

    head_kernel<<<NBLK, 256, 0, stream>>>(h, out1_w, out1_b, out2_w, out2_b, gs, N_NUM);
    final_kernel<<<1, 64, 0, stream>>>(gs, ro_w, ro_b, out);
}